// Round 6
// baseline (261.512 us; speedup 1.0000x reference)
//
#include <hip/hip_runtime.h>
#include <hip/hip_bf16.h>

#define B_  4
#define T_  2048
#define D_  768
#define H_  12
#define DH_ 64
#define FF_ 3072

typedef __attribute__((ext_vector_type(8))) short bf16x8;
typedef __attribute__((ext_vector_type(4))) float f32x4;
typedef __attribute__((ext_vector_type(4))) unsigned short us4;

#define MFMA16(a, b, c) __builtin_amdgcn_mfma_f32_16x16x32_bf16((a), (b), (c), 0, 0, 0)

__device__ __forceinline__ unsigned short f2bf(float f) {
    union { float f; unsigned u; } v; v.f = f;
    unsigned r = v.u + 0x7fffu + ((v.u >> 16) & 1u);
    return (unsigned short)(r >> 16);
}

// async global->LDS, 16B per lane. LDS dest must be wave-uniform; HW adds lane*16.
__device__ __forceinline__ void gload_lds16(const unsigned short* gp, unsigned short* lp) {
    __builtin_amdgcn_global_load_lds(
        (const __attribute__((address_space(1))) unsigned int*)gp,
        (__attribute__((address_space(3))) unsigned int*)lp,
        16, 0, 0);
}

// ---------------- weight convert + transpose: src[K][N] f32 -> dst[N][K] bf16 ----------
__global__ __launch_bounds__(256) void tcvt_kernel(
    const float* __restrict__ src, unsigned short* __restrict__ dst, int K, int N)
{
    __shared__ float tile[32][33];
    const int bx = blockIdx.x * 32;  // N dim
    const int by = blockIdx.y * 32;  // K dim
    const int tx = threadIdx.x, ty = threadIdx.y;  // 32 x 8
#pragma unroll
    for (int i = 0; i < 32; i += 8)
        tile[ty + i][tx] = src[(size_t)(by + ty + i) * N + bx + tx];
    __syncthreads();
#pragma unroll
    for (int i = 0; i < 32; i += 8)
        dst[(size_t)(bx + ty + i) * K + by + tx] = f2bf(tile[tx][ty + i]);
}

// batched version for the four 768x768 weights (Wq,Wk,Wv,Wo -> contiguous dst)
__global__ __launch_bounds__(256) void tcvt4_kernel(
    const float* __restrict__ s0, const float* __restrict__ s1,
    const float* __restrict__ s2, const float* __restrict__ s3,
    unsigned short* __restrict__ dst)
{
    __shared__ float tile[32][33];
    const int z = blockIdx.z;
    const float* src = (z == 0) ? s0 : (z == 1) ? s1 : (z == 2) ? s2 : s3;
    unsigned short* d = dst + (size_t)z * 589824;
    const int bx = blockIdx.x * 32;
    const int by = blockIdx.y * 32;
    const int tx = threadIdx.x, ty = threadIdx.y;
#pragma unroll
    for (int i = 0; i < 32; i += 8)
        tile[ty + i][tx] = src[(size_t)(by + ty + i) * 768 + bx + tx];
    __syncthreads();
#pragma unroll
    for (int i = 0; i < 32; i += 8)
        d[(size_t)(bx + ty + i) * 768 + by + tx] = f2bf(tile[tx][ty + i]);
}

// ---------------- LayerNorm: fp32 in -> bf16 out ----------------
__global__ __launch_bounds__(256) void ln_kernel(
    const float* __restrict__ x, const float* __restrict__ g,
    const float* __restrict__ be, unsigned short* __restrict__ out)
{
    const int row = blockIdx.x;
    const int t = threadIdx.x;
    const float* xr = x + (size_t)row * D_;
    float v0 = xr[t], v1 = xr[t + 256], v2 = xr[t + 512];
    float s = v0 + v1 + v2;
    float s2 = v0 * v0 + v1 * v1 + v2 * v2;
#pragma unroll
    for (int o = 1; o < 64; o <<= 1) {
        s  += __shfl_xor(s,  o);
        s2 += __shfl_xor(s2, o);
    }
    __shared__ float rs[4], rq[4];
    const int wave = t >> 6;
    if ((t & 63) == 0) { rs[wave] = s; rq[wave] = s2; }
    __syncthreads();
    s  = rs[0] + rs[1] + rs[2] + rs[3];
    s2 = rq[0] + rq[1] + rq[2] + rq[3];
    const float mu = s * (1.0f / D_);
    const float var = s2 * (1.0f / D_) - mu * mu;
    const float rstd = rsqrtf(var + 1e-5f);
    unsigned short* orow = out + (size_t)row * D_;
    orow[t]       = f2bf((v0 - mu) * rstd * g[t]       + be[t]);
    orow[t + 256] = f2bf((v1 - mu) * rstd * g[t + 256] + be[t + 256]);
    orow[t + 512] = f2bf((v2 - mu) * rstd * g[t + 512] + be[t + 512]);
}

// ---------------- GEMM: C[M][N] = A[M][K] * Bt[N][K]^T + bias ----------------
// m97-structure: wave-tile 64x64 (acc 4x4), BK=64, simple sync/gload/sync/compute
// loop; latency hiding via multi-block co-residency.
// WAVES=4: BM=128,BN=128, 256 thr, waves 2x2, LDS 32KB (~3 blocks/CU).
// WAVES=8: BM=256,BN=128, 512 thr, waves 4x2, LDS 48KB (for small-N GEMMs).
// LDS rows = 64 shorts (128B), 8 x 16B blocks; block b of row r stored at b^(r&7)
// (via pre-swizzled global SOURCE, gload dest linear; ds_read XORs same key).
// This exact geometry measured 0 bank conflicts (round 3).
// 1D grid, N-fastest, bijective XCD swizzle.
// MODE 0: bf16 out; MODE 2: gelu->bf16; MODE 3: fp32 = acc+bias+resid;
// MODE 4: fused QKV routing (Q,K bf16 [M][768]; V transposed out3[b][n][t]).
template<int MODE, int WAVES>
__global__ __launch_bounds__(WAVES * 64, (WAVES == 4) ? 3 : 2) void gemmK(
    const unsigned short* __restrict__ A,
    const unsigned short* __restrict__ Bt,
    const float* __restrict__ bias,
    const float* __restrict__ bias2,
    const float* __restrict__ bias3,
    const float* __restrict__ resid,
    void* __restrict__ outp,
    void* __restrict__ out2,
    void* __restrict__ out3,
    int N, int K, int nTilesN)
{
    constexpr int BM = (WAVES == 4) ? 128 : 256;
    __shared__ __align__(16) unsigned short As[BM * 64];
    __shared__ __align__(16) unsigned short Bs[128 * 64];

    // bijective XCD swizzle (m204)
    const int nwg = gridDim.x;
    const int q = nwg >> 3, rr = nwg & 7;
    const int xcd = blockIdx.x & 7, loc = blockIdx.x >> 3;
    const int swz = (xcd < rr ? xcd * (q + 1) : rr * (q + 1) + (xcd - rr) * q) + loc;
    const int m0 = (swz / nTilesN) * BM;
    const int n0 = (swz % nTilesN) * 128;

    const int tid = threadIdx.x;
    const int wv = tid >> 6;
    const int lane = tid & 63;
    const int wr = wv >> 1;          // M wave index
    const int wc = wv & 1;           // N wave index

    f32x4 zero4 = {0.0f, 0.0f, 0.0f, 0.0f};
    f32x4 acc[4][4];
#pragma unroll
    for (int i = 0; i < 4; ++i)
#pragma unroll
        for (int j = 0; j < 4; ++j) acc[i][j] = zero4;

    // staging: chunks of 8 rows x 64 shorts (1KB). lane -> (lrow=lane>>3, blk=lane&7);
    // source col-block = blk ^ lrow  (== blk ^ (LDS_row & 7), chunk bases %8 == 0)
    constexpr int ACH = BM / WAVES / 8;     // A chunks per wave (4)
    constexpr int BCH = 128 / WAVES / 8;    // B chunks per wave (4 or 2)
    const int lrow = lane >> 3;
    const int scb = (lane & 7) ^ lrow;
    const unsigned short* ag = A + (size_t)(m0 + wv * (BM / WAVES) + lrow) * K + scb * 8;
    const unsigned short* bg = Bt + (size_t)(n0 + wv * (128 / WAVES) + lrow) * K + scb * 8;
    unsigned short* aLds = As + wv * (BM / WAVES) * 64;
    unsigned short* bLds = Bs + wv * (128 / WAVES) * 64;

    // fragment-read setup
    const int fr = lane & 15;
    const int fg = lane >> 4;        // 0..3
    const int sw = fr & 7;
    const int aRow = (wr * 64 + fr) * 64;   // + mm*16*64
    const int bRow = (wc * 64 + fr) * 64;   // + nn*16*64

    const int nk = K >> 6;
    for (int kt = 0; kt < nk; ++kt) {
        const int k0 = kt << 6;
        __syncthreads();
#pragma unroll
        for (int c = 0; c < ACH; ++c)
            gload_lds16(ag + k0 + (size_t)c * 8 * K, aLds + c * 512);
#pragma unroll
        for (int c = 0; c < BCH; ++c)
            gload_lds16(bg + k0 + (size_t)c * 8 * K, bLds + c * 512);
        __syncthreads();   // compiler emits vmcnt(0) drain here (m97 behavior)

#pragma unroll
        for (int kk = 0; kk < 2; ++kk) {
            bf16x8 afr[4], bfr[4];
            const int cb = ((kk * 4 + fg) ^ sw) << 3;
#pragma unroll
            for (int mm = 0; mm < 4; ++mm)
                afr[mm] = *(const bf16x8*)(As + aRow + mm * 1024 + cb);
#pragma unroll
            for (int nn = 0; nn < 4; ++nn)
                bfr[nn] = *(const bf16x8*)(Bs + bRow + nn * 1024 + cb);
#pragma unroll
            for (int mm = 0; mm < 4; ++mm)
#pragma unroll
                for (int nn = 0; nn < 4; ++nn)
                    acc[mm][nn] = MFMA16(afr[mm], bfr[nn], acc[mm][nn]);
        }
    }

    // ---- epilogue
    const int lc = lane & 15;
    const int lr = (lane >> 4) * 4;
#pragma unroll
    for (int mm = 0; mm < 4; ++mm) {
        const int gm0 = m0 + wr * 64 + mm * 16 + lr;
#pragma unroll
        for (int nn = 0; nn < 4; ++nn) {
            const int gn = n0 + wc * 64 + nn * 16 + lc;
            if (MODE == 4) {
                if (gn < 1536) {
                    const float bv = (gn < 768) ? bias[gn] : bias2[gn - 768];
                    unsigned short* o = (gn < 768) ? (unsigned short*)outp : (unsigned short*)out2;
                    const int col = (gn < 768) ? gn : gn - 768;
#pragma unroll
                    for (int r = 0; r < 4; ++r)
                        o[(size_t)(gm0 + r) * 768 + col] = f2bf(acc[mm][nn][r] + bv);
                } else {
                    const float bv = bias3[gn - 1536];
                    const int b = gm0 / T_;
                    const int tl = gm0 - b * T_;
                    us4 pk;
#pragma unroll
                    for (int r = 0; r < 4; ++r) pk[r] = f2bf(acc[mm][nn][r] + bv);
                    *(us4*)((unsigned short*)out3 + ((size_t)(b * D_ + gn - 1536)) * T_ + tl) = pk;
                }
            } else {
                const float bv = bias[gn];
#pragma unroll
                for (int r = 0; r < 4; ++r) {
                    const int gm = gm0 + r;
                    float v = acc[mm][nn][r] + bv;
                    if (MODE == 0) {
                        ((unsigned short*)outp)[(size_t)gm * N + gn] = f2bf(v);
                    } else if (MODE == 2) {
                        v = 0.5f * v * (1.0f + erff(v * 0.70710678118654752f));
                        ((unsigned short*)outp)[(size_t)gm * N + gn] = f2bf(v);
                    } else if (MODE == 3) {
                        ((float*)outp)[(size_t)gm * N + gn] = v + resid[(size_t)gm * N + gn];
                    }
                }
            }
        }
    }
}

// ---------------- banded flash attention ----------------
// block = 256 threads (4 waves), handles (b, h, 64-query tile)
// K/V window = [t0, t1), KW <= 192
__global__ __launch_bounds__(256) void attn_kernel(
    const unsigned short* __restrict__ Q,    // [B*T][768]
    const unsigned short* __restrict__ Kg,   // [B*T][768]
    const unsigned short* __restrict__ Vt,   // [B][768][T]
    unsigned short* __restrict__ ctx)        // [B*T][768]
{
    __shared__ __align__(16) unsigned short Qs[64][72];
    __shared__ __align__(16) unsigned short KP[192 * 72];   // Ks[192][72], later Ps[64][200]
    __shared__ __align__(16) unsigned short Vts[64][200];

    const int tid = threadIdx.x;
    const int lane = tid & 63;
    const int w = tid >> 6;
    const int bid = blockIdx.x;
    const int qt = bid & 31;
    const int h = (bid >> 5) % H_;
    const int b = bid / (32 * H_);
    const int qs = qt * 64;
    const int t0 = qs >= 64 ? qs - 64 : 0;
    const int t1 = (qs + 128 < T_) ? qs + 128 : T_;
    const int KW = t1 - t0;

    // stage Q (64 rows x 64 cols)
    for (int s = tid; s < 512; s += 256) {
        const int r = s >> 3, c8 = (s & 7) << 3;
        *(uint4*)&Qs[r][c8] =
            *(const uint4*)&Q[((size_t)(b * T_ + qs + r)) * D_ + h * DH_ + c8];
    }
    // stage K (192 rows x 64), zero-filled beyond window
    unsigned short* Ks = KP;
    for (int s = tid; s < 1536; s += 256) {
        const int r = s >> 3, c8 = (s & 7) << 3;
        uint4 val = {0, 0, 0, 0};
        if (r < KW)
            val = *(const uint4*)&Kg[((size_t)(b * T_ + t0 + r)) * D_ + h * DH_ + c8];
        *(uint4*)&Ks[r * 72 + c8] = val;
    }
    // stage V^T (64 dh-rows x 192 key-cols), zero-filled beyond window
    for (int s = tid; s < 1536; s += 256) {
        const int r = s / 24, c8 = (s % 24) << 3;
        uint4 val = {0, 0, 0, 0};
        if (c8 < KW)
            val = *(const uint4*)&Vt[((size_t)((b * H_ + h) * DH_ + r)) * T_ + t0 + c8];
        *(uint4*)&Vts[r][c8] = val;
    }
    __syncthreads();

    // S = Q K^T : per wave 16 q-rows x 192 keys, 12 col-frags, K=64 (2 ksteps)
    f32x4 zero4 = {0.0f, 0.0f, 0.0f, 0.0f};
    f32x4 sa[12];
#pragma unroll
    for (int i = 0; i < 12; ++i) sa[i] = zero4;
#pragma unroll
    for (int ks = 0; ks < 2; ++ks) {
        const bf16x8 aq = *(const bf16x8*)&Qs[w * 16 + (lane & 15)][ks * 32 + (lane >> 4) * 8];
#pragma unroll
        for (int cf = 0; cf < 12; ++cf) {
            const bf16x8 bk = *(const bf16x8*)&Ks[(cf * 16 + (lane & 15)) * 72 + ks * 32 + (lane >> 4) * 8];
            sa[cf] = MFMA16(aq, bk, sa[cf]);
        }
    }
    __syncthreads();   // everyone done reading Ks before Ps overwrites it

    // mask + softmax (row = q, spread over 16 lanes x 12 frags)
    const int lq = w * 16 + (lane >> 4) * 4;
    float mx[4] = {-1e30f, -1e30f, -1e30f, -1e30f};
#pragma unroll
    for (int cf = 0; cf < 12; ++cf) {
        const int key = t0 + cf * 16 + (lane & 15);
#pragma unroll
        for (int r = 0; r < 4; ++r) {
            const int dd = (qs + lq + r) - key;
            const bool ok = (key < t1) && (dd <= 64) && (dd >= -64);
            const float sv = ok ? sa[cf][r] * 0.125f : -1e30f;
            sa[cf][r] = sv;
            mx[r] = fmaxf(mx[r], sv);
        }
    }
#pragma unroll
    for (int r = 0; r < 4; ++r)
#pragma unroll
        for (int o = 1; o < 16; o <<= 1)
            mx[r] = fmaxf(mx[r], __shfl_xor(mx[r], o));

    unsigned short* Ps = KP;   // [64][200]
    float sm[4] = {0.0f, 0.0f, 0.0f, 0.0f};
#pragma unroll
    for (int cf = 0; cf < 12; ++cf) {
#pragma unroll
        for (int r = 0; r < 4; ++r) {
            const float p = __expf(sa[cf][r] - mx[r]);   // masked -> 0
            sm[r] += p;
            Ps[(lq + r) * 200 + cf * 16 + (lane & 15)] = f2bf(p);
        }
    }
#pragma unroll
    for (int r = 0; r < 4; ++r)
#pragma unroll
        for (int o = 1; o < 16; o <<= 1)
            sm[r] += __shfl_xor(sm[r], o);

    // O = P V : per wave 16 q-rows x 64 dh, 4 col-frags, K=192 (6 ksteps)
    f32x4 oa[4];
#pragma unroll
    for (int i = 0; i < 4; ++i) oa[i] = zero4;
#pragma unroll
    for (int ks = 0; ks < 6; ++ks) {
        const bf16x8 ap = *(const bf16x8*)&Ps[(w * 16 + (lane & 15)) * 200 + ks * 32 + (lane >> 4) * 8];
#pragma unroll
        for (int nf = 0; nf < 4; ++nf) {
            const bf16x8 bv = *(const bf16x8*)&Vts[nf * 16 + (lane & 15)][ks * 32 + (lane >> 4) * 8];
            oa[nf] = MFMA16(ap, bv, oa[nf]);
        }
    }
#pragma unroll
    for (int nf = 0; nf < 4; ++nf) {
#pragma unroll
        for (int r = 0; r < 4; ++r) {
            const float o = oa[nf][r] / sm[r];
            ctx[((size_t)(b * T_ + qs + lq + r)) * D_ + h * DH_ + nf * 16 + (lane & 15)] = f2bf(o);
        }
    }
}

// ---------------- orchestration ----------------
extern "C" void kernel_launch(void* const* d_in, const int* in_sizes, int n_in,
                              void* d_out, int out_size, void* d_ws, size_t ws_size,
                              hipStream_t stream)
{
    const float* x   = (const float*)d_in[0];
    const float* Wq  = (const float*)d_in[1];
    const float* bq  = (const float*)d_in[2];
    const float* Wk  = (const float*)d_in[3];
    const float* bk  = (const float*)d_in[4];
    const float* Wv  = (const float*)d_in[5];
    const float* bv  = (const float*)d_in[6];
    const float* Wo  = (const float*)d_in[7];
    const float* bo  = (const float*)d_in[8];
    const float* W1  = (const float*)d_in[9];
    const float* b1  = (const float*)d_in[10];
    const float* W2  = (const float*)d_in[11];
    const float* b2  = (const float*)d_in[12];
    const float* g1  = (const float*)d_in[13];
    const float* be1 = (const float*)d_in[14];
    const float* g2  = (const float*)d_in[15];
    const float* be2 = (const float*)d_in[16];
    float* out = (float*)d_out;

    // workspace layout (elements):
    // wqkv_t [2304][768] bf16, wo_t, w1_t, w2_t | hbuf | qbuf | x2 f32 | kbuf | vtb | ffb over kbuf..
    unsigned short* wqkv_t = (unsigned short*)d_ws;        // 3 x [768][768]
    unsigned short* wo_t = wqkv_t + 3 * 589824;
    unsigned short* w1_t = wo_t + 589824;                  // [3072][768]
    unsigned short* w2_t = w1_t + 2359296;                 // [768][3072]
    unsigned short* hbuf = w2_t + 2359296;                 // h1, later ctx
    unsigned short* qbuf = hbuf + 6291456;                 // q, later h2
    float* x2 = (float*)(qbuf + 6291456);                  // fp32 [8192][768]
    unsigned short* kbuf = (unsigned short*)(x2 + 6291456);
    unsigned short* vtb  = kbuf + 6291456;                 // [4][768][2048]
    unsigned short* ffb  = kbuf;                           // [8192][3072] over k/vt/extra

    dim3 tb(32, 8);
    tcvt4_kernel<<<dim3(24, 24, 4), tb, 0, stream>>>(Wq, Wk, Wv, Wo, wqkv_t);
    tcvt_kernel<<<dim3(96, 24), tb, 0, stream>>>(W1, w1_t, 768, 3072);
    tcvt_kernel<<<dim3(24, 96), tb, 0, stream>>>(W2, w2_t, 3072, 768);

    ln_kernel<<<8192, 256, 0, stream>>>(x, g1, be1, hbuf);

    // fused QKV: N = 2304, routes Q->qbuf, K->kbuf, V->vtb(transposed)
    gemmK<4, 4><<<64 * 18, 256, 0, stream>>>(
        hbuf, wqkv_t, bq, bk, bv, nullptr, qbuf, kbuf, vtb, 2304, 768, 18);

    attn_kernel<<<1536, 256, 0, stream>>>(qbuf, kbuf, vtb, hbuf);   // ctx -> hbuf

    gemmK<3, 8><<<32 * 6, 512, 0, stream>>>(
        hbuf, wo_t, bo, nullptr, nullptr, x, x2, nullptr, nullptr, 768, 768, 6);

    ln_kernel<<<8192, 256, 0, stream>>>(x2, g2, be2, qbuf);         // h2 -> qbuf

    gemmK<2, 4><<<64 * 24, 256, 0, stream>>>(
        qbuf, w1_t, b1, nullptr, nullptr, nullptr, ffb, nullptr, nullptr, 3072, 768, 24);

    gemmK<3, 8><<<32 * 6, 512, 0, stream>>>(
        ffb, w2_t, b2, nullptr, nullptr, x2, out, nullptr, nullptr, 768, 3072, 6);
}

// Round 7
// 239.500 us; speedup vs baseline: 1.0919x; 1.0919x over previous
//
#include <hip/hip_runtime.h>
#include <hip/hip_bf16.h>

#define B_  4
#define T_  2048
#define D_  768
#define H_  12
#define DH_ 64
#define FF_ 3072

typedef __attribute__((ext_vector_type(8))) short bf16x8;
typedef __attribute__((ext_vector_type(4))) float f32x4;
typedef __attribute__((ext_vector_type(4))) unsigned short us4;

#define MFMA16(a, b, c) __builtin_amdgcn_mfma_f32_16x16x32_bf16((a), (b), (c), 0, 0, 0)

__device__ __forceinline__ unsigned short f2bf(float f) {
    union { float f; unsigned u; } v; v.f = f;
    unsigned r = v.u + 0x7fffu + ((v.u >> 16) & 1u);
    return (unsigned short)(r >> 16);
}
__device__ __forceinline__ float bf2f(unsigned short s) {
    union { unsigned u; float f; } v; v.u = ((unsigned)s) << 16;
    return v.f;
}

// async global->LDS, 16B per lane. LDS dest must be wave-uniform; HW adds lane*16.
__device__ __forceinline__ void gload_lds16(const unsigned short* gp, unsigned short* lp) {
    __builtin_amdgcn_global_load_lds(
        (const __attribute__((address_space(1))) unsigned int*)gp,
        (__attribute__((address_space(3))) unsigned int*)lp,
        16, 0, 0);
}

// ---------------- weight convert + transpose: src[K][N] f32 -> dst[N][K] bf16 ----------
__global__ __launch_bounds__(256) void tcvt_kernel(
    const float* __restrict__ src, unsigned short* __restrict__ dst, int K, int N)
{
    __shared__ float tile[32][33];
    const int bx = blockIdx.x * 32;  // N dim
    const int by = blockIdx.y * 32;  // K dim
    const int tx = threadIdx.x, ty = threadIdx.y;  // 32 x 8
#pragma unroll
    for (int i = 0; i < 32; i += 8)
        tile[ty + i][tx] = src[(size_t)(by + ty + i) * N + bx + tx];
    __syncthreads();
#pragma unroll
    for (int i = 0; i < 32; i += 8)
        dst[(size_t)(bx + ty + i) * K + by + tx] = f2bf(tile[tx][ty + i]);
}

// batched version for the four 768x768 weights (Wq,Wk,Wv,Wo -> contiguous dst)
__global__ __launch_bounds__(256) void tcvt4_kernel(
    const float* __restrict__ s0, const float* __restrict__ s1,
    const float* __restrict__ s2, const float* __restrict__ s3,
    unsigned short* __restrict__ dst)
{
    __shared__ float tile[32][33];
    const int z = blockIdx.z;
    const float* src = (z == 0) ? s0 : (z == 1) ? s1 : (z == 2) ? s2 : s3;
    unsigned short* d = dst + (size_t)z * 589824;
    const int bx = blockIdx.x * 32;
    const int by = blockIdx.y * 32;
    const int tx = threadIdx.x, ty = threadIdx.y;
#pragma unroll
    for (int i = 0; i < 32; i += 8)
        tile[ty + i][tx] = src[(size_t)(by + ty + i) * 768 + bx + tx];
    __syncthreads();
#pragma unroll
    for (int i = 0; i < 32; i += 8)
        d[(size_t)(bx + ty + i) * 768 + by + tx] = f2bf(tile[tx][ty + i]);
}

// ---------------- LayerNorm: fp32 in -> bf16 out ----------------
__global__ __launch_bounds__(256) void ln_kernel(
    const float* __restrict__ x, const float* __restrict__ g,
    const float* __restrict__ be, unsigned short* __restrict__ out)
{
    const int row = blockIdx.x;
    const int t = threadIdx.x;
    const float* xr = x + (size_t)row * D_;
    float v0 = xr[t], v1 = xr[t + 256], v2 = xr[t + 512];
    float s = v0 + v1 + v2;
    float s2 = v0 * v0 + v1 * v1 + v2 * v2;
#pragma unroll
    for (int o = 1; o < 64; o <<= 1) {
        s  += __shfl_xor(s,  o);
        s2 += __shfl_xor(s2, o);
    }
    __shared__ float rs[4], rq[4];
    const int wave = t >> 6;
    if ((t & 63) == 0) { rs[wave] = s; rq[wave] = s2; }
    __syncthreads();
    s  = rs[0] + rs[1] + rs[2] + rs[3];
    s2 = rq[0] + rq[1] + rq[2] + rq[3];
    const float mu = s * (1.0f / D_);
    const float var = s2 * (1.0f / D_) - mu * mu;
    const float rstd = rsqrtf(var + 1e-5f);
    unsigned short* orow = out + (size_t)row * D_;
    orow[t]       = f2bf((v0 - mu) * rstd * g[t]       + be[t]);
    orow[t + 256] = f2bf((v1 - mu) * rstd * g[t + 256] + be[t + 256]);
    orow[t + 512] = f2bf((v2 - mu) * rstd * g[t + 512] + be[t + 512]);
}

// ---- fused split-K reduce + residual + LayerNorm (Wo path) ----
// x2 = p0 + p1 + bo + x (fp32, stored); h2 = LN(x2)*g2+be2 (bf16)
__global__ __launch_bounds__(256) void reduce_ln_kernel(
    const unsigned short* __restrict__ p0, const unsigned short* __restrict__ p1,
    const float* __restrict__ x, const float* __restrict__ bo,
    const float* __restrict__ g, const float* __restrict__ be,
    float* __restrict__ x2, unsigned short* __restrict__ h2)
{
    const int row = blockIdx.x;
    const int t = threadIdx.x;
    const size_t base = (size_t)row * D_;
    float v[3];
    float s = 0.0f, s2 = 0.0f;
#pragma unroll
    for (int j = 0; j < 3; ++j) {
        const int c = t + j * 256;
        const float vv = bf2f(p0[base + c]) + bf2f(p1[base + c]) + bo[c] + x[base + c];
        v[j] = vv;
        x2[base + c] = vv;
        s += vv; s2 += vv * vv;
    }
#pragma unroll
    for (int o = 1; o < 64; o <<= 1) {
        s  += __shfl_xor(s,  o);
        s2 += __shfl_xor(s2, o);
    }
    __shared__ float rs[4], rq[4];
    const int wave = t >> 6;
    if ((t & 63) == 0) { rs[wave] = s; rq[wave] = s2; }
    __syncthreads();
    s  = rs[0] + rs[1] + rs[2] + rs[3];
    s2 = rq[0] + rq[1] + rq[2] + rq[3];
    const float mu = s * (1.0f / D_);
    const float var = s2 * (1.0f / D_) - mu * mu;
    const float rstd = rsqrtf(var + 1e-5f);
#pragma unroll
    for (int j = 0; j < 3; ++j) {
        const int c = t + j * 256;
        h2[base + c] = f2bf((v[j] - mu) * rstd * g[c] + be[c]);
    }
}

// ---- split-K reduce + bias + residual (FF2 path, fp32 out) ----
__global__ __launch_bounds__(256) void reduce_out_kernel(
    const unsigned short* __restrict__ p0, const unsigned short* __restrict__ p1,
    const float* __restrict__ x2, const float* __restrict__ b2,
    float* __restrict__ out)
{
    const int n4 = B_ * T_ * D_ / 4;
    for (int i = blockIdx.x * 256 + threadIdx.x; i < n4; i += gridDim.x * 256) {
        const us4 a = ((const us4*)p0)[i];
        const us4 b = ((const us4*)p1)[i];
        const float4 xr = ((const float4*)x2)[i];
        const int col = (i * 4) % D_;
        float4 o;
        o.x = bf2f(a[0]) + bf2f(b[0]) + b2[col]     + xr.x;
        o.y = bf2f(a[1]) + bf2f(b[1]) + b2[col + 1] + xr.y;
        o.z = bf2f(a[2]) + bf2f(b[2]) + b2[col + 2] + xr.z;
        o.w = bf2f(a[3]) + bf2f(b[3]) + b2[col + 3] + xr.w;
        ((float4*)out)[i] = o;
    }
}

// ---------------- GEMM: C[M][N] = A[M][K(stride)] * Bt[N][K]^T ----------------
// Round-3 proven structure: BM=128, BN=128, BK=64; 512 threads (8 waves 4x2),
// wave-tile 32x64 (acc 2x4); LDS 32KB; ~4 blocks/CU co-residency does the
// latency hiding. XOR-swizzled LDS via pre-swizzled global SOURCE (gload dest
// linear; ds_read same XOR) -> measured 0 bank conflicts.
// 1D grid over (ks, mTile, nTile), N-fastest; bijective XCD swizzle.
// Split-K: ks = swz / nTilesMN, K range [ks*kLen, (ks+1)*kLen).
// MODE 0: bf16 out [M][N]
// MODE 2: gelu(exact) -> bf16 out [M][N]
// MODE 4: fused QKV routing (Q,K bf16 [M][768]; V transposed out3[b][n][t])
// MODE 5: bf16 partial out at outp + ks*partStride (no bias)
template<int MODE>
__global__ __launch_bounds__(512) void gemm512(
    const unsigned short* __restrict__ A,
    const unsigned short* __restrict__ Bt,
    const float* __restrict__ bias,
    const float* __restrict__ bias2,
    const float* __restrict__ bias3,
    void* __restrict__ outp,
    void* __restrict__ out2,
    void* __restrict__ out3,
    int N, int K, int kLen, int nTilesN, int nTilesMN, long partStride)
{
    __shared__ __align__(16) unsigned short As[128 * 64];
    __shared__ __align__(16) unsigned short Bs[128 * 64];

    // bijective XCD swizzle (m204)
    const int nwg = gridDim.x;
    const int q = nwg >> 3, rr = nwg & 7;
    const int xcd = blockIdx.x & 7, loc = blockIdx.x >> 3;
    const int swz = (xcd < rr ? xcd * (q + 1) : rr * (q + 1) + (xcd - rr) * q) + loc;
    const int ks  = swz / nTilesMN;
    const int rem = swz - ks * nTilesMN;
    const int m0 = (rem / nTilesN) * 128;
    const int n0 = (rem % nTilesN) * 128;
    const int kOff = ks * kLen;

    const int tid = threadIdx.x;
    const int wv = tid >> 6;
    const int lane = tid & 63;
    const int wr = wv >> 1;          // 0..3
    const int wc = wv & 1;           // 0..1

    f32x4 zero4 = {0.0f, 0.0f, 0.0f, 0.0f};
    f32x4 acc[2][4];
#pragma unroll
    for (int i = 0; i < 2; ++i)
#pragma unroll
        for (int j = 0; j < 4; ++j) acc[i][j] = zero4;

    // staging: each wave stages 16 rows (2 issues x 8 rows) of A and of B.
    // lane -> (row=lane>>3, blk=lane&7); source col-block = blk ^ (row&7)
    const int lrow = lane >> 3;
    const int scb = (lane & 7) ^ lrow;
    const size_t ag0 = (size_t)(m0 + wv * 16 + lrow) * K + kOff + scb * 8;
    const size_t ag1 = ag0 + (size_t)8 * K;
    const size_t bg0 = (size_t)(n0 + wv * 16 + lrow) * K + kOff + scb * 8;
    const size_t bg1 = bg0 + (size_t)8 * K;
    unsigned short* AsW = As + wv * 1024;
    unsigned short* BsW = Bs + wv * 1024;

    const int fr = lane & 15;        // fragment row within 16
    const int fg = lane >> 4;        // 0..3 col-block group
    const int sw = fr & 7;           // XOR key for ds_read

    const int nk = kLen >> 6;
    for (int kt = 0; kt < nk; ++kt) {
        const int k0 = kt << 6;
        __syncthreads();
        gload_lds16(A  + ag0 + k0, AsW);
        gload_lds16(A  + ag1 + k0, AsW + 512);
        gload_lds16(Bt + bg0 + k0, BsW);
        gload_lds16(Bt + bg1 + k0, BsW + 512);
        __syncthreads();
#pragma unroll
        for (int kk = 0; kk < 2; ++kk) {
            bf16x8 afr[2], bfr[4];
#pragma unroll
            for (int mm = 0; mm < 2; ++mm) {
                const int row = wr * 32 + mm * 16 + fr;
                afr[mm] = *(const bf16x8*)(As + row * 64 + (((kk * 4 + fg) ^ sw) << 3));
            }
#pragma unroll
            for (int nn = 0; nn < 4; ++nn) {
                const int row = wc * 64 + nn * 16 + fr;
                bfr[nn] = *(const bf16x8*)(Bs + row * 64 + (((kk * 4 + fg) ^ sw) << 3));
            }
#pragma unroll
            for (int mm = 0; mm < 2; ++mm)
#pragma unroll
                for (int nn = 0; nn < 4; ++nn)
                    acc[mm][nn] = MFMA16(afr[mm], bfr[nn], acc[mm][nn]);
        }
    }

    const int lc = lane & 15;
    const int lr = (lane >> 4) * 4;
#pragma unroll
    for (int mm = 0; mm < 2; ++mm) {
        const int gm0 = m0 + wr * 32 + mm * 16 + lr;
#pragma unroll
        for (int nn = 0; nn < 4; ++nn) {
            const int gn = n0 + wc * 64 + nn * 16 + lc;
            if (MODE == 4) {
                if (gn < 1536) {
                    const float bv = (gn < 768) ? bias[gn] : bias2[gn - 768];
                    unsigned short* o = (gn < 768) ? (unsigned short*)outp : (unsigned short*)out2;
                    const int col = (gn < 768) ? gn : gn - 768;
#pragma unroll
                    for (int r = 0; r < 4; ++r)
                        o[(size_t)(gm0 + r) * 768 + col] = f2bf(acc[mm][nn][r] + bv);
                } else {
                    const float bv = bias3[gn - 1536];
                    const int b = gm0 / T_;
                    const int tl = gm0 - b * T_;
                    us4 pk;
#pragma unroll
                    for (int r = 0; r < 4; ++r) pk[r] = f2bf(acc[mm][nn][r] + bv);
                    *(us4*)((unsigned short*)out3 + ((size_t)(b * D_ + gn - 1536)) * T_ + tl) = pk;
                }
            } else if (MODE == 5) {
                unsigned short* o = (unsigned short*)outp + (size_t)ks * partStride;
#pragma unroll
                for (int r = 0; r < 4; ++r)
                    o[(size_t)(gm0 + r) * N + gn] = f2bf(acc[mm][nn][r]);
            } else {
                const float bv = bias[gn];
#pragma unroll
                for (int r = 0; r < 4; ++r) {
                    const int gm = gm0 + r;
                    float v = acc[mm][nn][r] + bv;
                    if (MODE == 0) {
                        ((unsigned short*)outp)[(size_t)gm * N + gn] = f2bf(v);
                    } else if (MODE == 2) {
                        v = 0.5f * v * (1.0f + erff(v * 0.70710678118654752f));
                        ((unsigned short*)outp)[(size_t)gm * N + gn] = f2bf(v);
                    }
                }
            }
        }
    }
}

// ---------------- banded flash attention ----------------
// block = 256 threads (4 waves), handles (b, h, 64-query tile)
// K/V window = [t0, t1), KW <= 192
__global__ __launch_bounds__(256) void attn_kernel(
    const unsigned short* __restrict__ Q,    // [B*T][768]
    const unsigned short* __restrict__ Kg,   // [B*T][768]
    const unsigned short* __restrict__ Vt,   // [B][768][T]
    unsigned short* __restrict__ ctx)        // [B*T][768]
{
    __shared__ __align__(16) unsigned short Qs[64][72];
    __shared__ __align__(16) unsigned short KP[192 * 72];   // Ks[192][72], later Ps[64][200]
    __shared__ __align__(16) unsigned short Vts[64][200];

    const int tid = threadIdx.x;
    const int lane = tid & 63;
    const int w = tid >> 6;
    const int bid = blockIdx.x;
    const int qt = bid & 31;
    const int h = (bid >> 5) % H_;
    const int b = bid / (32 * H_);
    const int qs = qt * 64;
    const int t0 = qs >= 64 ? qs - 64 : 0;
    const int t1 = (qs + 128 < T_) ? qs + 128 : T_;
    const int KW = t1 - t0;

    // stage Q (64 rows x 64 cols)
    for (int s = tid; s < 512; s += 256) {
        const int r = s >> 3, c8 = (s & 7) << 3;
        *(uint4*)&Qs[r][c8] =
            *(const uint4*)&Q[((size_t)(b * T_ + qs + r)) * D_ + h * DH_ + c8];
    }
    // stage K (192 rows x 64), zero-filled beyond window
    unsigned short* Ks = KP;
    for (int s = tid; s < 1536; s += 256) {
        const int r = s >> 3, c8 = (s & 7) << 3;
        uint4 val = {0, 0, 0, 0};
        if (r < KW)
            val = *(const uint4*)&Kg[((size_t)(b * T_ + t0 + r)) * D_ + h * DH_ + c8];
        *(uint4*)&Ks[r * 72 + c8] = val;
    }
    // stage V^T (64 dh-rows x 192 key-cols), zero-filled beyond window
    for (int s = tid; s < 1536; s += 256) {
        const int r = s / 24, c8 = (s % 24) << 3;
        uint4 val = {0, 0, 0, 0};
        if (c8 < KW)
            val = *(const uint4*)&Vt[((size_t)((b * H_ + h) * DH_ + r)) * T_ + t0 + c8];
        *(uint4*)&Vts[r][c8] = val;
    }
    __syncthreads();

    // S = Q K^T : per wave 16 q-rows x 192 keys, 12 col-frags, K=64 (2 ksteps)
    f32x4 zero4 = {0.0f, 0.0f, 0.0f, 0.0f};
    f32x4 sa[12];
#pragma unroll
    for (int i = 0; i < 12; ++i) sa[i] = zero4;
#pragma unroll
    for (int ks = 0; ks < 2; ++ks) {
        const bf16x8 aq = *(const bf16x8*)&Qs[w * 16 + (lane & 15)][ks * 32 + (lane >> 4) * 8];
#pragma unroll
        for (int cf = 0; cf < 12; ++cf) {
            const bf16x8 bk = *(const bf16x8*)&Ks[(cf * 16 + (lane & 15)) * 72 + ks * 32 + (lane >> 4) * 8];
            sa[cf] = MFMA16(aq, bk, sa[cf]);
        }
    }
    __syncthreads();   // everyone done reading Ks before Ps overwrites it

    // mask + softmax (row = q, spread over 16 lanes x 12 frags)
    const int lq = w * 16 + (lane >> 4) * 4;
    float mx[4] = {-1e30f, -1e30f, -1e30f, -1e30f};
#pragma unroll
    for (int cf = 0; cf < 12; ++cf) {
        const int key = t0 + cf * 16 + (lane & 15);
#pragma unroll
        for (int r = 0; r < 4; ++r) {
            const int dd = (qs + lq + r) - key;
            const bool ok = (key < t1) && (dd <= 64) && (dd >= -64);
            const float sv = ok ? sa[cf][r] * 0.125f : -1e30f;
            sa[cf][r] = sv;
            mx[r] = fmaxf(mx[r], sv);
        }
    }
#pragma unroll
    for (int r = 0; r < 4; ++r)
#pragma unroll
        for (int o = 1; o < 16; o <<= 1)
            mx[r] = fmaxf(mx[r], __shfl_xor(mx[r], o));

    unsigned short* Ps = KP;   // [64][200]
    float sm[4] = {0.0f, 0.0f, 0.0f, 0.0f};
#pragma unroll
    for (int cf = 0; cf < 12; ++cf) {
#pragma unroll
        for (int r = 0; r < 4; ++r) {
            const float p = __expf(sa[cf][r] - mx[r]);   // masked -> 0
            sm[r] += p;
            Ps[(lq + r) * 200 + cf * 16 + (lane & 15)] = f2bf(p);
        }
    }
#pragma unroll
    for (int r = 0; r < 4; ++r)
#pragma unroll
        for (int o = 1; o < 16; o <<= 1)
            sm[r] += __shfl_xor(sm[r], o);

    // O = P V : per wave 16 q-rows x 64 dh, 4 col-frags, K=192 (6 ksteps)
    f32x4 oa[4];
#pragma unroll
    for (int i = 0; i < 4; ++i) oa[i] = zero4;
#pragma unroll
    for (int ks = 0; ks < 6; ++ks) {
        const bf16x8 ap = *(const bf16x8*)&Ps[(w * 16 + (lane & 15)) * 200 + ks * 32 + (lane >> 4) * 8];
#pragma unroll
        for (int nf = 0; nf < 4; ++nf) {
            const bf16x8 bv = *(const bf16x8*)&Vts[nf * 16 + (lane & 15)][ks * 32 + (lane >> 4) * 8];
            oa[nf] = MFMA16(ap, bv, oa[nf]);
        }
    }
#pragma unroll
    for (int nf = 0; nf < 4; ++nf) {
#pragma unroll
        for (int r = 0; r < 4; ++r) {
            const float o = oa[nf][r] / sm[r];
            ctx[((size_t)(b * T_ + qs + lq + r)) * D_ + h * DH_ + nf * 16 + (lane & 15)] = f2bf(o);
        }
    }
}

// ---------------- orchestration ----------------
extern "C" void kernel_launch(void* const* d_in, const int* in_sizes, int n_in,
                              void* d_out, int out_size, void* d_ws, size_t ws_size,
                              hipStream_t stream)
{
    const float* x   = (const float*)d_in[0];
    const float* Wq  = (const float*)d_in[1];
    const float* bq  = (const float*)d_in[2];
    const float* Wk  = (const float*)d_in[3];
    const float* bk  = (const float*)d_in[4];
    const float* Wv  = (const float*)d_in[5];
    const float* bv  = (const float*)d_in[6];
    const float* Wo  = (const float*)d_in[7];
    const float* bo  = (const float*)d_in[8];
    const float* W1  = (const float*)d_in[9];
    const float* b1  = (const float*)d_in[10];
    const float* W2  = (const float*)d_in[11];
    const float* b2  = (const float*)d_in[12];
    const float* g1  = (const float*)d_in[13];
    const float* be1 = (const float*)d_in[14];
    const float* g2  = (const float*)d_in[15];
    const float* be2 = (const float*)d_in[16];
    float* out = (float*)d_out;

    // workspace layout (elements):
    // wqkv_t [2304][768] bf16, wo_t, w1_t, w2_t | hbuf | qbuf | x2 f32 | kbuf | vtb | ffb over kbuf..
    unsigned short* wqkv_t = (unsigned short*)d_ws;        // 3 x [768][768]
    unsigned short* wo_t = wqkv_t + 3 * 589824;
    unsigned short* w1_t = wo_t + 589824;                  // [3072][768]
    unsigned short* w2_t = w1_t + 2359296;                 // [768][3072]
    unsigned short* hbuf = w2_t + 2359296;                 // h1, later ctx, later FF2-partials
    unsigned short* qbuf = hbuf + 6291456;                 // q, later h2
    float* x2 = (float*)(qbuf + 6291456);                  // fp32 [8192][768]
    unsigned short* kbuf = (unsigned short*)(x2 + 6291456); // k, later Wo-partials
    unsigned short* vtb  = kbuf + 6291456;                 // [4][768][2048]
    unsigned short* ffb  = kbuf;                           // [8192][3072] over k/vt/extra

    dim3 tb(32, 8);
    tcvt4_kernel<<<dim3(24, 24, 4), tb, 0, stream>>>(Wq, Wk, Wv, Wo, wqkv_t);
    tcvt_kernel<<<dim3(96, 24), tb, 0, stream>>>(W1, w1_t, 768, 3072);
    tcvt_kernel<<<dim3(24, 96), tb, 0, stream>>>(W2, w2_t, 3072, 768);

    ln_kernel<<<8192, 256, 0, stream>>>(x, g1, be1, hbuf);

    // fused QKV: N = 2304, routes Q->qbuf, K->kbuf, V->vtb(transposed)
    gemm512<4><<<64 * 18, 512, 0, stream>>>(
        hbuf, wqkv_t, bq, bk, bv, qbuf, kbuf, vtb, 2304, 768, 768, 18, 64 * 18, 0);

    attn_kernel<<<1536, 256, 0, stream>>>(qbuf, kbuf, vtb, hbuf);   // ctx -> hbuf

    // Wo: split-K S=2 (K'=384), bf16 partials into dead kbuf/vtb region
    gemm512<5><<<64 * 6 * 2, 512, 0, stream>>>(
        hbuf, wo_t, nullptr, nullptr, nullptr, kbuf, nullptr, nullptr,
        768, 768, 384, 6, 64 * 6, 6291456);

    // fused reduce + residual + LN2: x2 (fp32) and h2 (bf16 -> qbuf)
    reduce_ln_kernel<<<8192, 256, 0, stream>>>(
        kbuf, kbuf + 6291456, x, bo, g2, be2, x2, qbuf);

    // FF1: gelu -> ffb (overwrites Wo partials; they are dead)
    gemm512<2><<<64 * 24, 512, 0, stream>>>(
        qbuf, w1_t, b1, nullptr, nullptr, ffb, nullptr, nullptr,
        3072, 768, 768, 24, 64 * 24, 0);

    // FF2: split-K S=2 (K'=1536), bf16 partials into dead hbuf/qbuf region
    gemm512<5><<<64 * 6 * 2, 512, 0, stream>>>(
        ffb, w2_t, nullptr, nullptr, nullptr, hbuf, nullptr, nullptr,
        768, 3072, 1536, 6, 64 * 6, 6291456);

    reduce_out_kernel<<<2048, 256, 0, stream>>>(
        hbuf, hbuf + 6291456, x2, b2, out);
}